// Round 12
// baseline (441.573 us; speedup 1.0000x reference)
//
#include <hip/hip_runtime.h>
#include <math.h>

#define Cc     8
#define FIELD  7
#define PAD    3
#define TW     32        // tile width
#define TH     16        // tile height
#define QSTR   39        // mrf_iter qs row stride (uint4)
#define NSTG   (22*QSTR) // 858 staged uint4 per tile (mrf_iter)
#define Q1S    56        // pair: q_in stage stride; rows 30 (h0-7..h0+22), cols w0-11..
#define NST1   (30*Q1S)  // 1680
#define Q2S    49        // pair: q_mid stride; 24 rows (h0-4..h0+19), cols w0-8..w0+39
#define BB     32
#define HH     384
#define WW     384
#define NB     4         // batches per block in mrf_iter
#define NSLOT  64        // 8 dy' x 8 dx slots (dx==7 zero-pad) for a row-PAIR
#define UCLIP  13.815510557964274f   // -log(1e-6)

typedef __attribute__((ext_vector_type(8))) short short8;  // 8 bf16 = 4 VGPRs
typedef __attribute__((ext_vector_type(4))) float f32x4;   // MFMA C/D

__device__ __forceinline__ unsigned short f2bf(float f) {   // RNE fp32->bf16
    unsigned u = __float_as_uint(f);
    u += 0x7FFFu + ((u >> 16) & 1u);
    return (unsigned short)(u >> 16);
}
__device__ __forceinline__ unsigned short f2h(float f) {    // RNE fp32->fp16
    return __builtin_bit_cast(unsigned short, (_Float16)f);
}
__device__ __forceinline__ float hlo(unsigned u) {
    return (float)__builtin_bit_cast(_Float16, (unsigned short)(u & 0xFFFFu));
}
__device__ __forceinline__ float hhi(unsigned u) {
    return (float)__builtin_bit_cast(_Float16, (unsigned short)(u >> 16));
}
__device__ __forceinline__ uint4 softmax_pack(const float o[Cc]) {
    float mm = o[0];
#pragma unroll
    for (int d = 1; d < Cc; ++d) mm = fmaxf(mm, o[d]);
    float ss = 0.f, e[Cc];
#pragma unroll
    for (int d = 0; d < Cc; ++d) { e[d] = __expf(o[d] - mm); ss += e[d]; }
    float inv = 1.f / ss;
    uint4 qo;
    qo.x = f2bf(e[0] * inv) | ((unsigned)f2bf(e[1] * inv) << 16);
    qo.y = f2bf(e[2] * inv) | ((unsigned)f2bf(e[3] * inv) << 16);
    qo.z = f2bf(e[4] * inv) | ((unsigned)f2bf(e[5] * inv) << 16);
    qo.w = f2bf(e[6] * inv) | ((unsigned)f2bf(e[7] * inv) << 16);
    return qo;
}

// ---------------------------------------------------------------------------
// prep_w: row-pair fused weight table, dx-major slot layout (R6/R7-verified).
// ---------------------------------------------------------------------------
__global__ __launch_bounds__(256)
void prep_w(const float* __restrict__ kw, const float* __restrict__ sw,
            unsigned short* __restrict__ wtab) {
    int it = blockIdx.x * 256 + threadIdx.x;      // (slot, j=cin)
    if (it >= NSLOT * 8) return;
    int s = it >> 3, j = it & 7;
    int dyp = s >> 3, dx = s & 7;
#pragma unroll
    for (int n = 0; n < 16; ++n) {
        int h = n >> 3, d = n & 7;
        int dy = dyp - h;
        float a = 0.f;
        if (dy >= 0 && dy < FIELD && dx < 7) {
            int tap = dy * 7 + dx;
#pragma unroll
            for (int c = 0; c < Cc; ++c) {
                float kv = (c == j) ? 0.f : kw[(tap * Cc + j) * Cc + c];
                a = fmaf(kv, sw[c * Cc + d], a);
            }
        }
        wtab[(s * 16 + n) * 8 + j] = f2bf(a);
    }
}

// ---------------------------------------------------------------------------
// init_qv: q0 = softmax(x) bf16x8; v = b - u@W (u = min(lse-x, UCLIP)).
// 2 px/thread ILP (R11-verified). v fp16 (vh) when half!=0, else fp32 (vf).
// ---------------------------------------------------------------------------
__global__ __launch_bounds__(256)
void init_qv(const float* __restrict__ x, const float* __restrict__ sw,
             const float* __restrict__ sb,
             uint4* __restrict__ q0, float* __restrict__ vf,
             uint4* __restrict__ vh, int half) {
    const long long HALF = (long long)BB * HH * WW / 2;
    const long long p0 = (long long)blockIdx.x * 256 + threadIdx.x;
    const long long p1 = p0 + HALF;

    const float4* xp0 = (const float4*)(x + p0 * Cc);
    const float4* xp1 = (const float4*)(x + p1 * Cc);
    float4 a0 = xp0[0], a1 = xp0[1];
    float4 b0 = xp1[0], b1 = xp1[1];

    float xa[Cc] = {a0.x, a0.y, a0.z, a0.w, a1.x, a1.y, a1.z, a1.w};
    float xb[Cc] = {b0.x, b0.y, b0.z, b0.w, b1.x, b1.y, b1.z, b1.w};

    float ma = xa[0], mb = xb[0];
#pragma unroll
    for (int c = 1; c < Cc; ++c) { ma = fmaxf(ma, xa[c]); mb = fmaxf(mb, xb[c]); }
    float sa = 0.f, sb_ = 0.f, ea[Cc], eb[Cc];
#pragma unroll
    for (int c = 0; c < Cc; ++c) {
        ea[c] = __expf(xa[c] - ma); sa += ea[c];
        eb[c] = __expf(xb[c] - mb); sb_ += eb[c];
    }
    float ia = 1.f / sa, ib = 1.f / sb_;
    uint4 qa, qb;
    qa.x = f2bf(ea[0] * ia) | ((unsigned)f2bf(ea[1] * ia) << 16);
    qa.y = f2bf(ea[2] * ia) | ((unsigned)f2bf(ea[3] * ia) << 16);
    qa.z = f2bf(ea[4] * ia) | ((unsigned)f2bf(ea[5] * ia) << 16);
    qa.w = f2bf(ea[6] * ia) | ((unsigned)f2bf(ea[7] * ia) << 16);
    qb.x = f2bf(eb[0] * ib) | ((unsigned)f2bf(eb[1] * ib) << 16);
    qb.y = f2bf(eb[2] * ib) | ((unsigned)f2bf(eb[3] * ib) << 16);
    qb.z = f2bf(eb[4] * ib) | ((unsigned)f2bf(eb[5] * ib) << 16);
    qb.w = f2bf(eb[6] * ib) | ((unsigned)f2bf(eb[7] * ib) << 16);
    q0[p0] = qa;
    q0[p1] = qb;

    float lsea = ma + __logf(sa), lseb = mb + __logf(sb_);
    float ua[Cc], ub[Cc];
#pragma unroll
    for (int c = 0; c < Cc; ++c) {
        ua[c] = fminf(lsea - xa[c], UCLIP);
        ub[c] = fminf(lseb - xb[c], UCLIP);
    }
    float va[Cc], vb[Cc];
#pragma unroll
    for (int d = 0; d < Cc; ++d) {
        float aa = sb[d], ab = sb[d];
#pragma unroll
        for (int c = 0; c < Cc; ++c) {
            float w = sw[c * Cc + d];
            aa = fmaf(-ua[c], w, aa);
            ab = fmaf(-ub[c], w, ab);
        }
        va[d] = aa; vb[d] = ab;
    }
    if (half) {
        uint4 voa, vob;
        voa.x = f2h(va[0]) | ((unsigned)f2h(va[1]) << 16);
        voa.y = f2h(va[2]) | ((unsigned)f2h(va[3]) << 16);
        voa.z = f2h(va[4]) | ((unsigned)f2h(va[5]) << 16);
        voa.w = f2h(va[6]) | ((unsigned)f2h(va[7]) << 16);
        vob.x = f2h(vb[0]) | ((unsigned)f2h(vb[1]) << 16);
        vob.y = f2h(vb[2]) | ((unsigned)f2h(vb[3]) << 16);
        vob.z = f2h(vb[4]) | ((unsigned)f2h(vb[5]) << 16);
        vob.w = f2h(vb[6]) | ((unsigned)f2h(vb[7]) << 16);
        vh[p0] = voa;
        vh[p1] = vob;
    } else {
        float4* vpa = (float4*)(vf + p0 * Cc);
        vpa[0] = make_float4(va[0], va[1], va[2], va[3]);
        vpa[1] = make_float4(va[4], va[5], va[6], va[7]);
        float4* vpb = (float4*)(vf + p1 * Cc);
        vpb[0] = make_float4(vb[0], vb[1], vb[2], vb[3]);
        vpb[1] = make_float4(vb[4], vb[5], vb[6], vb[7]);
    }
}

// ---------------------------------------------------------------------------
// mrf_pair: TWO fused mean-field iterations; intermediate q stays in LDS.
// Stage q_in on rows [h0-7,h0+23) x cols [w0-11,w0+45) (30x56, zero-pad SAME).
// Iter A: compute q_mid on M = rows [h0-4,h0+20) x cols [w0-8,w0+40) (24x48)
//   via 18 wave-units of the verified 4rowx16col K-loop; out-of-image -> 0.
//   Index maps (derived): staged row = 4rg+dyp, staged col = 16cg+m+g+4dxb.
// Iter B: verified loop on q_mid (stride Q2S): row = r0+1+dyp,
//   col = cx+m+g+5 (+4dxb); epilogue identical to mrf_iter (write q_out).
// Per-pixel math identical to two unfused mrf_iter calls -> bit-identical q.
// Saves the 151 MB intermediate q round-trip per pair.
// ---------------------------------------------------------------------------
__global__ __launch_bounds__(512)
void mrf_pair(const uint4* __restrict__ qin,
              const unsigned short* __restrict__ wtab,
              const uint4* __restrict__ vh,
              uint4* __restrict__ qout) {
    __shared__ __align__(16) uint4 qs1[NST1];      // 26880 B
    __shared__ __align__(16) uint4 qs2[24 * Q2S];  // 18816 B

    const int tid = threadIdx.x;
    const int wv  = tid >> 6;
    const int l   = tid & 63;
    const int m   = l & 15;
    const int g   = l >> 4;
    const int p   = g & 1;
    const int hb  = g >> 1;

    const int w0 = blockIdx.x * TW;
    const int h0 = blockIdx.y * TH;
    const int b  = blockIdx.z;
    const long long BSTR = (long long)HH * WW;
    const uint4 zz = make_uint4(0, 0, 0, 0);

    // --- weights (once) ---
    short8 bw[8][2];
#pragma unroll
    for (int dyq = 0; dyq < 8; ++dyq)
#pragma unroll
        for (int dxb = 0; dxb < 2; ++dxb) {
            int s = dyq * 8 + 4 * dxb + g;
            uint4 t = *(const uint4*)(wtab + (s * 16 + m) * 8);
            bw[dyq][dxb] = __builtin_bit_cast(short8, t);
        }

    // --- stage q_in (30x56) ---
    const uint4* qb = qin + (long long)b * BSTR;
    for (int s = tid; s < NST1; s += 512) {
        int sy = s / Q1S, sx = s - sy * Q1S;
        int gh = h0 + sy - 7, gw = w0 + sx - 11;
        uint4 val = zz;
        if (gh >= 0 && gh < HH && gw >= 0 && gw < WW)
            val = qb[(long long)gh * WW + gw];
        qs1[s] = val;
    }
    __syncthreads();

    // --- iter A: 18 units (6 row-groups x 3 col-groups) on M (24x48) ---
    for (int u = wv; u < 18; u += 8) {
        int rg = u / 3, cg = u - 3 * rg;
        f32x4 acc0 = (f32x4){0.f, 0.f, 0.f, 0.f};
        f32x4 acc1 = (f32x4){0.f, 0.f, 0.f, 0.f};
        const int colb = 16 * cg + m + g;
#pragma unroll
        for (int dyp = 0; dyp < 10; ++dyp) {
            const int rb = (4 * rg + dyp) * Q1S + colb;
#pragma unroll
            for (int dxb = 0; dxb < 2; ++dxb) {
                short8 qv = *(const short8*)&qs1[rb + 4 * dxb];
                if (dyp < 8)
                    acc0 = __builtin_amdgcn_mfma_f32_16x16x32_bf16(bw[dyp][dxb], qv, acc0, 0, 0, 0);
                if (dyp >= 2)
                    acc1 = __builtin_amdgcn_mfma_f32_16x16x32_bf16(bw[dyp - 2][dxb], qv, acc1, 0, 0, 0);
            }
        }
        float o[Cc];
#pragma unroll
        for (int tt = 0; tt < 4; ++tt) {
            float s0v = __shfl_xor(acc0[tt], 16);
            float s1v = __shfl_xor(acc1[tt], 16);
            o[tt]     = p ? s1v      : acc0[tt];
            o[4 + tt] = p ? acc1[tt] : s0v;
        }
        const int my = 4 * rg + 2 * p + hb;
        const int mx = 16 * cg + m;
        const int gy = h0 + my - 4, gx = w0 + mx - 8;
        uint4 qo = zz;
        if (gy >= 0 && gy < HH && gx >= 0 && gx < WW) {
            uint4 vhv = vh[(long long)b * BSTR + (long long)gy * WW + gx];
            o[0] = hlo(vhv.x) - o[0]; o[1] = hhi(vhv.x) - o[1];
            o[2] = hlo(vhv.y) - o[2]; o[3] = hhi(vhv.y) - o[3];
            o[4] = hlo(vhv.z) - o[4]; o[5] = hhi(vhv.z) - o[5];
            o[6] = hlo(vhv.w) - o[6]; o[7] = hhi(vhv.w) - o[7];
            qo = softmax_pack(o);
        }
        qs2[my * Q2S + mx] = qo;
    }
    __syncthreads();

    // --- iter B: verified loop on q_mid ---
    const int r0 = 4 * (wv >> 1);
    const int cx = 16 * (wv & 1);
    const int row = r0 + 2 * p + hb;
    const int px  = cx + m;
    const long long pix = (long long)b * BSTR + (long long)(h0 + row) * WW + (w0 + px);

    f32x4 acc0 = (f32x4){0.f, 0.f, 0.f, 0.f};
    f32x4 acc1 = (f32x4){0.f, 0.f, 0.f, 0.f};
    const int colb2 = cx + m + g + 5;
#pragma unroll
    for (int dyp = 0; dyp < 10; ++dyp) {
        const int rb = (r0 + 1 + dyp) * Q2S + colb2;
#pragma unroll
        for (int dxb = 0; dxb < 2; ++dxb) {
            short8 qv = *(const short8*)&qs2[rb + 4 * dxb];
            if (dyp < 8)
                acc0 = __builtin_amdgcn_mfma_f32_16x16x32_bf16(bw[dyp][dxb], qv, acc0, 0, 0, 0);
            if (dyp >= 2)
                acc1 = __builtin_amdgcn_mfma_f32_16x16x32_bf16(bw[dyp - 2][dxb], qv, acc1, 0, 0, 0);
        }
    }
    float o[Cc];
#pragma unroll
    for (int tt = 0; tt < 4; ++tt) {
        float s0v = __shfl_xor(acc0[tt], 16);
        float s1v = __shfl_xor(acc1[tt], 16);
        o[tt]     = p ? s1v      : acc0[tt];
        o[4 + tt] = p ? acc1[tt] : s0v;
    }
    uint4 vhv = vh[pix];
    o[0] = hlo(vhv.x) - o[0]; o[1] = hhi(vhv.x) - o[1];
    o[2] = hlo(vhv.y) - o[2]; o[3] = hhi(vhv.y) - o[3];
    o[4] = hlo(vhv.z) - o[4]; o[5] = hhi(vhv.z) - o[5];
    o[6] = hlo(vhv.w) - o[6]; o[7] = hhi(vhv.w) - o[7];
    qout[pix] = softmax_pack(o);
}

// ---------------------------------------------------------------------------
// mrf_iter: R7/R8-verified iteration kernel (VHALF: v fp16 vs fp32).
// ---------------------------------------------------------------------------
template<int VHALF>
__global__ __launch_bounds__(512)
void mrf_iter(const uint4* __restrict__ qin,
              const unsigned short* __restrict__ wtab,
              const void* __restrict__ vsrc,
              uint4* __restrict__ qout,
              float* __restrict__ lout,
              int last) {
    __shared__ __align__(16) uint4 qs[2][NSTG];

    const int tid = threadIdx.x;
    const int wv  = tid >> 6;
    const int l   = tid & 63;
    const int m   = l & 15;
    const int g   = l >> 4;

    const int w0 = blockIdx.x * TW;
    const int h0 = blockIdx.y * TH;
    const int b0 = blockIdx.z * NB;

    const int r0 = 4 * (wv >> 1);
    const int cx = 16 * (wv & 1);

    const int p   = g & 1;
    const int row = r0 + 2 * p + (g >> 1);
    const int px  = cx + m;
    const long long pixoff = (long long)(h0 + row) * WW + (w0 + px);
    const long long BSTR   = (long long)HH * WW;

    short8 bw[8][2];
#pragma unroll
    for (int dyq = 0; dyq < 8; ++dyq)
#pragma unroll
        for (int dxb = 0; dxb < 2; ++dxb) {
            int s = dyq * 8 + 4 * dxb + g;
            uint4 t = *(const uint4*)(wtab + (s * 16 + m) * 8);
            bw[dyq][dxb] = __builtin_bit_cast(short8, t);
        }

    const int sy0 = tid / QSTR, sx0 = tid - sy0 * QSTR;
    const int gh0 = h0 + sy0 - PAD, gw0 = w0 + sx0 - PAD;
    const bool in0 = (gh0 >= 0 && gh0 < HH && gw0 >= 0 && gw0 < WW);
    const long long off0 = (long long)gh0 * WW + gw0;
    const int  s1  = tid + 512;
    const bool has1 = (s1 < NSTG);
    const int sy1 = s1 / QSTR, sx1 = s1 - sy1 * QSTR;
    const int gh1 = h0 + sy1 - PAD, gw1 = w0 + sx1 - PAD;
    const bool in1 = has1 && (gh1 >= 0 && gh1 < HH && gw1 >= 0 && gw1 < WW);
    const long long off1 = (long long)gh1 * WW + gw1;

    const uint4* qb = qin + b0 * BSTR;
    const uint4  zz = make_uint4(0, 0, 0, 0);

    uint4 c0 = in0 ? qb[off0] : zz;
    uint4 c1 = in1 ? qb[off1] : zz;
    uint4  vhv = zz;
    float4 v0, v1;
    if constexpr (VHALF) {
        vhv = ((const uint4*)vsrc)[b0 * BSTR + pixoff];
    } else {
        const float4* vp0 = (const float4*)((const float*)vsrc + (b0 * BSTR + pixoff) * Cc);
        v0 = vp0[0]; v1 = vp0[1];
    }
    qs[0][tid] = c0;
    if (has1) qs[0][s1] = c1;
    __syncthreads();

#pragma unroll
    for (int t = 0; t < NB; ++t) {
        uint4 n0 = zz, n1 = zz, vhn = zz;
        float4 vn0 = make_float4(0.f, 0.f, 0.f, 0.f), vn1 = vn0;
        if (t + 1 < NB) {
            const uint4* qbn = qb + (t + 1) * BSTR;
            n0 = in0 ? qbn[off0] : zz;
            n1 = in1 ? qbn[off1] : zz;
            if constexpr (VHALF) {
                vhn = ((const uint4*)vsrc)[(b0 + t + 1) * BSTR + pixoff];
            } else {
                const float4* vpn = (const float4*)((const float*)vsrc + ((b0 + t + 1) * BSTR + pixoff) * Cc);
                vn0 = vpn[0]; vn1 = vpn[1];
            }
        }

        f32x4 acc0 = (f32x4){0.f, 0.f, 0.f, 0.f};
        f32x4 acc1 = (f32x4){0.f, 0.f, 0.f, 0.f};
        const uint4* Q = qs[t & 1];
        const int colbase = cx + m + g;
#pragma unroll
        for (int dyp = 0; dyp < 10; ++dyp) {
            const int rb = (r0 + dyp) * QSTR + colbase;
#pragma unroll
            for (int dxb = 0; dxb < 2; ++dxb) {
                short8 qv = *(const short8*)&Q[rb + 4 * dxb];
                if (dyp < 8)
                    acc0 = __builtin_amdgcn_mfma_f32_16x16x32_bf16(bw[dyp][dxb], qv, acc0, 0, 0, 0);
                if (dyp >= 2)
                    acc1 = __builtin_amdgcn_mfma_f32_16x16x32_bf16(bw[dyp - 2][dxb], qv, acc1, 0, 0, 0);
            }
        }

        float o[Cc];
#pragma unroll
        for (int tt = 0; tt < 4; ++tt) {
            float s0v = __shfl_xor(acc0[tt], 16);
            float s1v = __shfl_xor(acc1[tt], 16);
            o[tt]     = p ? s1v      : acc0[tt];
            o[4 + tt] = p ? acc1[tt] : s0v;
        }

        float vv[Cc];
        if constexpr (VHALF) {
            vv[0] = hlo(vhv.x); vv[1] = hhi(vhv.x);
            vv[2] = hlo(vhv.y); vv[3] = hhi(vhv.y);
            vv[4] = hlo(vhv.z); vv[5] = hhi(vhv.z);
            vv[6] = hlo(vhv.w); vv[7] = hhi(vhv.w);
        } else {
            vv[0] = v0.x; vv[1] = v0.y; vv[2] = v0.z; vv[3] = v0.w;
            vv[4] = v1.x; vv[5] = v1.y; vv[6] = v1.z; vv[7] = v1.w;
        }
#pragma unroll
        for (int d = 0; d < Cc; ++d) o[d] = vv[d] - o[d];
        const long long pix = (b0 + t) * BSTR + pixoff;
        if (last) {
            float4* op = (float4*)(lout + pix * Cc);
            op[0] = make_float4(o[0], o[1], o[2], o[3]);
            op[1] = make_float4(o[4], o[5], o[6], o[7]);
        } else {
            qout[pix] = softmax_pack(o);
        }

        if (t + 1 < NB) {
            qs[(t + 1) & 1][tid] = n0;
            if (has1) qs[(t + 1) & 1][s1] = n1;
            __syncthreads();
            if constexpr (VHALF) { vhv = vhn; } else { v0 = vn0; v1 = vn1; }
        }
    }
}

extern "C" void kernel_launch(void* const* d_in, const int* in_sizes, int n_in,
                              void* d_out, int out_size, void* d_ws, size_t ws_size,
                              hipStream_t stream) {
    (void)in_sizes; (void)n_in; (void)out_size;
    const float* x  = (const float*)d_in[0];   // [32,384,384,8]
    const float* kw = (const float*)d_in[1];   // [7,7,8,8]
    const float* sw = (const float*)d_in[2];   // [8,8]
    const float* sb = (const float*)d_in[3];   // [8]

    const size_t QSZ = (size_t)BB * HH * WW * 16;   // 75,497,472 B (bf16x8)
    const size_t VSZ = (size_t)BB * HH * WW * 16;   // 75,497,472 B (fp16x8)
    uint4* qA = (uint4*)d_ws;
    uint4* qB = (uint4*)((char*)d_ws + QSZ);

    const long long npix = (long long)BB * HH * WW;
    dim3 grid(WW / TW, HH / TH, BB / NB);   // 12 x 24 x 8

    if (ws_size >= 2 * QSZ + VSZ + 16384) {
        // fp16-v path; iterations (1,2) and (3,4) fused via mrf_pair
        uint4* vh = (uint4*)((char*)d_ws + 2 * QSZ);
        unsigned short* wt = (unsigned short*)((char*)d_ws + 2 * QSZ + VSZ);
        prep_w<<<2, 256, 0, stream>>>(kw, sw, wt);
        init_qv<<<(int)(npix / 512), 256, 0, stream>>>(x, sw, sb, qA, nullptr, vh, 1);
        dim3 gridP(WW / TW, HH / TH, BB);   // 12 x 24 x 32
        mrf_pair<<<gridP, 512, 0, stream>>>(qA, wt, vh, qB);   // iters 1,2
        mrf_pair<<<gridP, 512, 0, stream>>>(qB, wt, vh, qA);   // iters 3,4
        mrf_iter<1><<<grid, 512, 0, stream>>>(qA, wt, vh, nullptr, (float*)d_out, 1);
    } else {
        // fallback: exact R7-verified fp32-v-in-d_out path
        float* vbuf = (float*)d_out;
        unsigned short* wt = (unsigned short*)((char*)d_ws + 2 * QSZ);
        prep_w<<<2, 256, 0, stream>>>(kw, sw, wt);
        init_qv<<<(int)(npix / 512), 256, 0, stream>>>(x, sw, sb, qA, vbuf, nullptr, 0);
        mrf_iter<0><<<grid, 512, 0, stream>>>(qA, wt, vbuf, qB, nullptr, 0);
        mrf_iter<0><<<grid, 512, 0, stream>>>(qB, wt, vbuf, qA, nullptr, 0);
        mrf_iter<0><<<grid, 512, 0, stream>>>(qA, wt, vbuf, qB, nullptr, 0);
        mrf_iter<0><<<grid, 512, 0, stream>>>(qB, wt, vbuf, qA, nullptr, 0);
        mrf_iter<0><<<grid, 512, 0, stream>>>(qA, wt, vbuf, nullptr, (float*)d_out, 1);
    }
}

// Round 14
// 345.733 us; speedup vs baseline: 1.2772x; 1.2772x over previous
//
#include <hip/hip_runtime.h>
#include <math.h>

#define Cc     8
#define FIELD  7
#define PAD    3
#define TW     32        // tile width
#define TH     16        // tile height
#define QSTR   39        // qs row stride (uint4); col 38 = pad col (staged, zero weight)
#define NSTG   (22*QSTR) // 858 staged uint4 per tile
#define BB     32
#define HH     384
#define WW     384
#define NB     4         // batches per block (software-pipelined)
#define NSLOT  64        // 8 dy' x 8 dx slots (dx==7 zero-pad) for a row-PAIR
#define IP     4         // pixels per thread in init_qv
#define UCLIP  13.815510557964274f   // -log(1e-6)

typedef __attribute__((ext_vector_type(8))) short short8;  // 8 bf16 = 4 VGPRs
typedef __attribute__((ext_vector_type(4))) float f32x4;   // MFMA C/D
typedef __attribute__((ext_vector_type(4))) float fvec4;   // native vec for nontemporal builtins

__device__ __forceinline__ unsigned short f2bf(float f) {   // RNE fp32->bf16
    unsigned u = __float_as_uint(f);
    u += 0x7FFFu + ((u >> 16) & 1u);
    return (unsigned short)(u >> 16);
}
__device__ __forceinline__ unsigned short f2h(float f) {    // RNE fp32->fp16
    return __builtin_bit_cast(unsigned short, (_Float16)f);
}
__device__ __forceinline__ float hlo(unsigned u) {
    return (float)__builtin_bit_cast(_Float16, (unsigned short)(u & 0xFFFFu));
}
__device__ __forceinline__ float hhi(unsigned u) {
    return (float)__builtin_bit_cast(_Float16, (unsigned short)(u >> 16));
}

// ---------------------------------------------------------------------------
// init_qv (+ folded prep_w): q0 = softmax(x) bf16x8; v = b - u@W
// (u = min(lse-x, UCLIP)); v fp16 (vh) when half!=0, else fp32 (vf).
// IP=4 pixels/thread at stride npix/4 -> 8 coalesced float4 loads in flight
// per thread (MLP for the latency-bound softmax/v chain). Math per pixel
// identical to the R8/R11-verified version (absmax-stable).
// Blocks 0-1 additionally compute the 64-slot fused weight table (dx-major,
// R6/R7-verified layout) -- removes the separate prep_w launch.
// ---------------------------------------------------------------------------
__global__ __launch_bounds__(256)
void init_qv(const float* __restrict__ x, const float* __restrict__ sw,
             const float* __restrict__ sb,
             uint4* __restrict__ q0, float* __restrict__ vf,
             uint4* __restrict__ vh, int half,
             const float* __restrict__ kw, unsigned short* __restrict__ wtab) {
    // --- folded prep_w (512 threads cover 512 (slot,j) items; 408 real) ---
    if (blockIdx.x < 2) {
        int it = blockIdx.x * 256 + threadIdx.x;
        if (it < NSLOT * 8) {
            int s = it >> 3, j = it & 7;
            int dyp = s >> 3, dx = s & 7;
#pragma unroll
            for (int n = 0; n < 16; ++n) {
                int h = n >> 3, d = n & 7;
                int dy = dyp - h;
                float a = 0.f;
                if (dy >= 0 && dy < FIELD && dx < 7) {
                    int tap = dy * 7 + dx;
#pragma unroll
                    for (int c = 0; c < Cc; ++c) {
                        float kv = (c == j) ? 0.f : kw[(tap * Cc + j) * Cc + c];
                        a = fmaf(kv, sw[c * Cc + d], a);
                    }
                }
                wtab[(s * 16 + n) * 8 + j] = f2bf(a);
            }
        }
    }

    const long long STRD = (long long)BB * HH * WW / IP;
    const long long pb = (long long)blockIdx.x * 256 + threadIdx.x;

    // --- issue all IP*2 loads up front (read-once: nontemporal) ---
    fvec4 xr[IP][2];
#pragma unroll
    for (int k = 0; k < IP; ++k) {
        const fvec4* xp = (const fvec4*)(x + (pb + k * STRD) * Cc);
        xr[k][0] = __builtin_nontemporal_load(xp);
        xr[k][1] = __builtin_nontemporal_load(xp + 1);
    }

#pragma unroll
    for (int k = 0; k < IP; ++k) {
        const long long p = pb + k * STRD;
        float xv[Cc] = {xr[k][0].x, xr[k][0].y, xr[k][0].z, xr[k][0].w,
                        xr[k][1].x, xr[k][1].y, xr[k][1].z, xr[k][1].w};
        float m = xv[0];
#pragma unroll
        for (int c = 1; c < Cc; ++c) m = fmaxf(m, xv[c]);
        float s = 0.f, e[Cc];
#pragma unroll
        for (int c = 0; c < Cc; ++c) { e[c] = __expf(xv[c] - m); s += e[c]; }
        float inv = 1.f / s;
        uint4 qo;
        qo.x = f2bf(e[0] * inv) | ((unsigned)f2bf(e[1] * inv) << 16);
        qo.y = f2bf(e[2] * inv) | ((unsigned)f2bf(e[3] * inv) << 16);
        qo.z = f2bf(e[4] * inv) | ((unsigned)f2bf(e[5] * inv) << 16);
        qo.w = f2bf(e[6] * inv) | ((unsigned)f2bf(e[7] * inv) << 16);
        q0[p] = qo;

        float lse = m + __logf(s);
        float u[Cc];
#pragma unroll
        for (int c = 0; c < Cc; ++c) u[c] = fminf(lse - xv[c], UCLIP);
        float vv[Cc];
#pragma unroll
        for (int d = 0; d < Cc; ++d) {
            float a = sb[d];
#pragma unroll
            for (int c = 0; c < Cc; ++c) a = fmaf(-u[c], sw[c * Cc + d], a);
            vv[d] = a;
        }
        if (half) {
            uint4 vo;
            vo.x = f2h(vv[0]) | ((unsigned)f2h(vv[1]) << 16);
            vo.y = f2h(vv[2]) | ((unsigned)f2h(vv[3]) << 16);
            vo.z = f2h(vv[4]) | ((unsigned)f2h(vv[5]) << 16);
            vo.w = f2h(vv[6]) | ((unsigned)f2h(vv[7]) << 16);
            vh[p] = vo;
        } else {
            float4* vp = (float4*)(vf + p * Cc);
            vp[0] = make_float4(vv[0], vv[1], vv[2], vv[3]);
            vp[1] = make_float4(vv[4], vv[5], vv[6], vv[7]);
        }
    }
}

// ---------------------------------------------------------------------------
// mrf_iter: R7/R8/R11-verified iteration kernel (VHALF: v fp16 vs fp32).
// NB=4 batch pipeline on double-buffered qs; operand-swapped row-pair MFMA
// (dx-major K, read-dedup, 0 bank conflicts); in-register softmax via
// shfl_xor(16); single barrier per tile. Last iteration writes fp32 logits
// with nontemporal stores (151 MB never re-read -> don't pollute L2/L3).
// ---------------------------------------------------------------------------
template<int VHALF>
__global__ __launch_bounds__(512)
void mrf_iter(const uint4* __restrict__ qin,
              const unsigned short* __restrict__ wtab,
              const void* __restrict__ vsrc,
              uint4* __restrict__ qout,
              float* __restrict__ lout,
              int last) {
    __shared__ __align__(16) uint4 qs[2][NSTG];

    const int tid = threadIdx.x;
    const int wv  = tid >> 6;
    const int l   = tid & 63;
    const int m   = l & 15;
    const int g   = l >> 4;

    const int w0 = blockIdx.x * TW;
    const int h0 = blockIdx.y * TH;
    const int b0 = blockIdx.z * NB;

    const int r0 = 4 * (wv >> 1);
    const int cx = 16 * (wv & 1);

    const int p   = g & 1;
    const int row = r0 + 2 * p + (g >> 1);
    const int px  = cx + m;
    const long long pixoff = (long long)(h0 + row) * WW + (w0 + px);
    const long long BSTR   = (long long)HH * WW;

    short8 bw[8][2];
#pragma unroll
    for (int dyq = 0; dyq < 8; ++dyq)
#pragma unroll
        for (int dxb = 0; dxb < 2; ++dxb) {
            int s = dyq * 8 + 4 * dxb + g;
            uint4 t = *(const uint4*)(wtab + (s * 16 + m) * 8);
            bw[dyq][dxb] = __builtin_bit_cast(short8, t);
        }

    const int sy0 = tid / QSTR, sx0 = tid - sy0 * QSTR;
    const int gh0 = h0 + sy0 - PAD, gw0 = w0 + sx0 - PAD;
    const bool in0 = (gh0 >= 0 && gh0 < HH && gw0 >= 0 && gw0 < WW);
    const long long off0 = (long long)gh0 * WW + gw0;
    const int  s1  = tid + 512;
    const bool has1 = (s1 < NSTG);
    const int sy1 = s1 / QSTR, sx1 = s1 - sy1 * QSTR;
    const int gh1 = h0 + sy1 - PAD, gw1 = w0 + sx1 - PAD;
    const bool in1 = has1 && (gh1 >= 0 && gh1 < HH && gw1 >= 0 && gw1 < WW);
    const long long off1 = (long long)gh1 * WW + gw1;

    const uint4* qb = qin + b0 * BSTR;
    const uint4  zz = make_uint4(0, 0, 0, 0);

    uint4 c0 = in0 ? qb[off0] : zz;
    uint4 c1 = in1 ? qb[off1] : zz;
    uint4  vhv = zz;
    float4 v0, v1;
    if constexpr (VHALF) {
        vhv = ((const uint4*)vsrc)[b0 * BSTR + pixoff];
    } else {
        const float4* vp0 = (const float4*)((const float*)vsrc + (b0 * BSTR + pixoff) * Cc);
        v0 = vp0[0]; v1 = vp0[1];
    }
    qs[0][tid] = c0;
    if (has1) qs[0][s1] = c1;
    __syncthreads();

#pragma unroll
    for (int t = 0; t < NB; ++t) {
        uint4 n0 = zz, n1 = zz, vhn = zz;
        float4 vn0 = make_float4(0.f, 0.f, 0.f, 0.f), vn1 = vn0;
        if (t + 1 < NB) {
            const uint4* qbn = qb + (t + 1) * BSTR;
            n0 = in0 ? qbn[off0] : zz;
            n1 = in1 ? qbn[off1] : zz;
            if constexpr (VHALF) {
                vhn = ((const uint4*)vsrc)[(b0 + t + 1) * BSTR + pixoff];
            } else {
                const float4* vpn = (const float4*)((const float*)vsrc + ((b0 + t + 1) * BSTR + pixoff) * Cc);
                vn0 = vpn[0]; vn1 = vpn[1];
            }
        }

        f32x4 acc0 = (f32x4){0.f, 0.f, 0.f, 0.f};
        f32x4 acc1 = (f32x4){0.f, 0.f, 0.f, 0.f};
        const uint4* Q = qs[t & 1];
        const int colbase = cx + m + g;
#pragma unroll
        for (int dyp = 0; dyp < 10; ++dyp) {
            const int rb = (r0 + dyp) * QSTR + colbase;
#pragma unroll
            for (int dxb = 0; dxb < 2; ++dxb) {
                short8 qv = *(const short8*)&Q[rb + 4 * dxb];
                if (dyp < 8)
                    acc0 = __builtin_amdgcn_mfma_f32_16x16x32_bf16(bw[dyp][dxb], qv, acc0, 0, 0, 0);
                if (dyp >= 2)
                    acc1 = __builtin_amdgcn_mfma_f32_16x16x32_bf16(bw[dyp - 2][dxb], qv, acc1, 0, 0, 0);
            }
        }

        float o[Cc];
#pragma unroll
        for (int tt = 0; tt < 4; ++tt) {
            float s0v = __shfl_xor(acc0[tt], 16);
            float s1v = __shfl_xor(acc1[tt], 16);
            o[tt]     = p ? s1v      : acc0[tt];
            o[4 + tt] = p ? acc1[tt] : s0v;
        }

        float vv[Cc];
        if constexpr (VHALF) {
            vv[0] = hlo(vhv.x); vv[1] = hhi(vhv.x);
            vv[2] = hlo(vhv.y); vv[3] = hhi(vhv.y);
            vv[4] = hlo(vhv.z); vv[5] = hhi(vhv.z);
            vv[6] = hlo(vhv.w); vv[7] = hhi(vhv.w);
        } else {
            vv[0] = v0.x; vv[1] = v0.y; vv[2] = v0.z; vv[3] = v0.w;
            vv[4] = v1.x; vv[5] = v1.y; vv[6] = v1.z; vv[7] = v1.w;
        }
#pragma unroll
        for (int d = 0; d < Cc; ++d) o[d] = vv[d] - o[d];
        const long long pix = (b0 + t) * BSTR + pixoff;
        if (last) {
            fvec4* op = (fvec4*)(lout + pix * Cc);
            fvec4 w0v = {o[0], o[1], o[2], o[3]};
            fvec4 w1v = {o[4], o[5], o[6], o[7]};
            __builtin_nontemporal_store(w0v, op);
            __builtin_nontemporal_store(w1v, op + 1);
        } else {
            float mm = o[0];
#pragma unroll
            for (int d = 1; d < Cc; ++d) mm = fmaxf(mm, o[d]);
            float ss = 0.f, e[Cc];
#pragma unroll
            for (int d = 0; d < Cc; ++d) { e[d] = __expf(o[d] - mm); ss += e[d]; }
            float inv = 1.f / ss;
            uint4 qo;
            qo.x = f2bf(e[0] * inv) | ((unsigned)f2bf(e[1] * inv) << 16);
            qo.y = f2bf(e[2] * inv) | ((unsigned)f2bf(e[3] * inv) << 16);
            qo.z = f2bf(e[4] * inv) | ((unsigned)f2bf(e[5] * inv) << 16);
            qo.w = f2bf(e[6] * inv) | ((unsigned)f2bf(e[7] * inv) << 16);
            qout[pix] = qo;
        }

        if (t + 1 < NB) {
            qs[(t + 1) & 1][tid] = n0;
            if (has1) qs[(t + 1) & 1][s1] = n1;
            __syncthreads();
            if constexpr (VHALF) { vhv = vhn; } else { v0 = vn0; v1 = vn1; }
        }
    }
}

extern "C" void kernel_launch(void* const* d_in, const int* in_sizes, int n_in,
                              void* d_out, int out_size, void* d_ws, size_t ws_size,
                              hipStream_t stream) {
    (void)in_sizes; (void)n_in; (void)out_size;
    const float* x  = (const float*)d_in[0];   // [32,384,384,8]
    const float* kw = (const float*)d_in[1];   // [7,7,8,8]
    const float* sw = (const float*)d_in[2];   // [8,8]
    const float* sb = (const float*)d_in[3];   // [8]

    const size_t QSZ = (size_t)BB * HH * WW * 16;   // 75,497,472 B (bf16x8)
    const size_t VSZ = (size_t)BB * HH * WW * 16;   // 75,497,472 B (fp16x8)
    uint4* qA = (uint4*)d_ws;
    uint4* qB = (uint4*)((char*)d_ws + QSZ);

    const long long npix = (long long)BB * HH * WW;
    dim3 grid(WW / TW, HH / TH, BB / NB);   // 12 x 24 x 8
    const int initBlocks = (int)(npix / (256 * IP));   // 4608

    if (ws_size >= 2 * QSZ + VSZ + 16384) {
        // fp16-v path: whole iteration working set {qA,qB,v} = 226.5 MB < L3
        uint4* vh = (uint4*)((char*)d_ws + 2 * QSZ);
        unsigned short* wt = (unsigned short*)((char*)d_ws + 2 * QSZ + VSZ);
        init_qv<<<initBlocks, 256, 0, stream>>>(x, sw, sb, qA, nullptr, vh, 1, kw, wt);
        mrf_iter<1><<<grid, 512, 0, stream>>>(qA, wt, vh, qB, nullptr, 0);
        mrf_iter<1><<<grid, 512, 0, stream>>>(qB, wt, vh, qA, nullptr, 0);
        mrf_iter<1><<<grid, 512, 0, stream>>>(qA, wt, vh, qB, nullptr, 0);
        mrf_iter<1><<<grid, 512, 0, stream>>>(qB, wt, vh, qA, nullptr, 0);
        mrf_iter<1><<<grid, 512, 0, stream>>>(qA, wt, vh, nullptr, (float*)d_out, 1);
    } else {
        // fallback: fp32-v-in-d_out path (R7-verified structure)
        float* vbuf = (float*)d_out;
        unsigned short* wt = (unsigned short*)((char*)d_ws + 2 * QSZ);
        init_qv<<<initBlocks, 256, 0, stream>>>(x, sw, sb, qA, vbuf, nullptr, 0, kw, wt);
        mrf_iter<0><<<grid, 512, 0, stream>>>(qA, wt, vbuf, qB, nullptr, 0);
        mrf_iter<0><<<grid, 512, 0, stream>>>(qB, wt, vbuf, qA, nullptr, 0);
        mrf_iter<0><<<grid, 512, 0, stream>>>(qA, wt, vbuf, qB, nullptr, 0);
        mrf_iter<0><<<grid, 512, 0, stream>>>(qB, wt, vbuf, qA, nullptr, 0);
        mrf_iter<0><<<grid, 512, 0, stream>>>(qA, wt, vbuf, nullptr, (float*)d_out, 1);
    }
}